// Round 9
// baseline (827.820 us; speedup 1.0000x reference)
//
#include <hip/hip_runtime.h>
#include <cstddef>

// DifferentiableRollout: x_{t+1} = x + DT * ( tanh([x,u]@W1 + b1) @ W2 + b2 )
// B=1024, T=200, SD=64, CD=32, H=512.  fp32 only (bf16 amplifies past the
// 1.245 absmax threshold; fp32 reorder noise alone is 0.25).
//
// History:
//  R5 (788us): weight preload arrays outside t-loop -> compiler remats as
//    just-in-time L2 loads.  Only no-spill/no-stall weight schedule found.
//  R8-R11: every explicit residency/chunk/prefetch scheme -> scratch spill
//    (28 GB HBM, 8.5ms) or latency exposure (960-1045us).
//  R12 (707us): packed fp32 (v_pk_fma_f32) halved FMA issue; VALU 77->51%.
//    Now idle-bound: 324 KB/CU/step of W1+W2 re-read from L2 (~65% of L2
//    ceiling) drained at 4 barriers/step.
//  R13 v1: infra failure ("container failed twice"), no counters.  Audit
//    found one plausible kernel fault: reinterpret float4/f2 loads of
//    __shared__ arrays without guaranteed 16B alignment (earlier rounds
//    got it by layout luck; R13 reshuffled declarations).  Hardened.
//
// R13 (resubmit): W2 fully LDS-resident + barrier A eliminated.
//  - GEMM1 remap: lane = ks*16 + jpl (4 K-slices of a j-pair in the SAME
//    wave).  After 24 pk_fma, butterfly __shfl_xor(16,32) finishes the
//    K-reduction in-register: part1 (32 KB) GONE, barrier A GONE.
//    Lane ks takes row ks (cndmask select, no runtime indexing), adds
//    bias, tanh x2, writes pbuf[ks][j0] (b64).
//  - W2 (128 KB) now fits in LDS: w2s + part2 16K + pbuf 8K + xcT 1.5K
//    + b1s 2K = 155.5 KB < 160 KB.  GEMM2 reads w2s lane-consecutive
//    (conflict-free).  L2 stream/step: 324 -> 196 KB/CU (W1 only, still
//    the proven R5/R12 remat idiom).
//  - 3 barriers/step: B (pbuf ready), C (part2 ready), D (state updated).
//  Verify: dur 480-580, LDS ~159K, FETCH ~14 MB / WRITE ~51 MB (spill
//  tripwire), VGPR <= 64, absmax ~0.25.

constexpr int B_  = 1024;
constexpr int T_  = 200;
constexpr int SD_ = 64;
constexpr int CD_ = 32;
constexpr int H_  = 512;
constexpr int KD_ = SD_ + CD_;   // 96
constexpr float DT_ = 0.1f;
constexpr int ROWS_ = 4;
constexpr int THREADS_ = 1024;
constexpr int KSLICES_ = 4;      // GEMM1 K split (lane bits 4-5)
constexpr int KLEN_ = KD_ / KSLICES_;   // 24
constexpr int CHUNK_ = 32;       // W2 rows per wave (H / 16 waves)

typedef float f2 __attribute__((ext_vector_type(2)));

__device__ __forceinline__ f2 bfly_ks(f2 v) {
    // sum across lanes differing in bits 4 (xor 16) and 5 (xor 32)
    f2 r;
    r.x = __shfl_xor(v.x, 16);  r.y = __shfl_xor(v.y, 16);
    v.x += r.x;                 v.y += r.y;
    r.x = __shfl_xor(v.x, 32);  r.y = __shfl_xor(v.y, 32);
    v.x += r.x;                 v.y += r.y;
    return v;
}

__global__ __launch_bounds__(THREADS_)
void rollout_r13_kernel(
    const float* __restrict__ x0,     // [B, SD]
    const float* __restrict__ ctrl,   // [B, T, CD]
    const float* __restrict__ W1,     // [KD, H]
    const float* __restrict__ b1,     // [H]
    const float* __restrict__ W2,     // [H, SD]
    const float* __restrict__ b2,     // [SD]
    float* __restrict__ out)          // [B, T+1, SD]
{
    __shared__ __align__(16) float w2s[H_][SD_];           // 128 KB, loaded once
    __shared__ __align__(16) float xcT[KD_][ROWS_];        // state+control, transposed
    __shared__ __align__(16) float pbuf[ROWS_][H_];        // tanh activations
    __shared__ __align__(16) float part2[ROWS_][16][SD_];  // GEMM2 partials
    __shared__ __align__(16) float b1s[H_];                // b1 copy

    const int tid = threadIdx.x;
    const int r0  = blockIdx.x * ROWS_;

    // ---- GEMM1 mapping: lane = ks*16 + jpl; wave owns 16 j-pairs ----
    const int lane = tid & 63;
    const int wvid = tid >> 6;          // 0..15
    const int ks   = lane >> 4;         // 0..3 (K-slice, in-wave)
    const int jpl  = lane & 15;
    const int j0   = (wvid * 16 + jpl) * 2;   // j-pair base, 0..510 even
    const int kbase = ks * KLEN_;
    f2 w1p[KLEN_];
    #pragma unroll
    for (int i = 0; i < KLEN_; ++i)
        w1p[i] = *(const f2*)&W1[(size_t)(kbase + i) * H_ + j0];  // remat idiom

    // ---- W2 -> LDS (flat coalesced copy, 8 float4 per thread) ----
    {
        const float4* __restrict__ src = (const float4*)W2;
        float4* dst = (float4*)&w2s[0][0];
        #pragma unroll
        for (int i = 0; i < 8; ++i)
            dst[i * THREADS_ + tid] = src[i * THREADS_ + tid];
    }
    if (tid < H_) b1s[tid] = b1[tid];

    // ---- GEMM2 mapping: wave wvid owns W2 rows [32wv,32wv+32), lane sl ----
    const int sl = lane;
    const int jb = wvid * CHUNK_;

    // reduce/update mapping (tid < 256)
    const int rf = (tid >> 6) & 3;
    const int sf = tid & 63;
    const float bs = b2[sf];

    // ctrl loader: tids [512, 640)
    const int  lt = tid - 512;
    const bool loader = (lt >= 0) && (lt < ROWS_ * CD_);
    const int  lr = (lt >> 5) & 3;
    const int  lc = lt & 31;
    const size_t ctrl_base = (size_t)(r0 + lr) * T_ * CD_ + lc;

    // ---- init: x0 into xcT + states[:,0,:], ctrl[0] into xcT ----
    if (tid < ROWS_ * SD_) {
        const float v = x0[(size_t)(r0 + rf) * SD_ + sf];
        xcT[sf][rf] = v;
        out[(size_t)(r0 + rf) * (T_ + 1) * SD_ + sf] = v;
    }
    if (loader) xcT[SD_ + lc][lr] = ctrl[ctrl_base];
    __syncthreads();   // covers xcT init, w2s copy, b1s copy

    for (int t = 0; t < T_; ++t) {
        // ---- prefetch next step's controls into a register ----
        float cpre = 0.f;
        if (loader && (t + 1 < T_))
            cpre = ctrl[ctrl_base + (size_t)(t + 1) * CD_];

        // ---- GEMM1 rank-24 partials: 4 rows x j-pair, packed fp32 ----
        f2 a0 = {0.f, 0.f}, a1 = {0.f, 0.f}, a2 = {0.f, 0.f}, a3 = {0.f, 0.f};
        #pragma unroll
        for (int i = 0; i < KLEN_; ++i) {
            const float4 xv = *(const float4*)&xcT[kbase + i][0];  // broadcast
            const f2 w = w1p[i];
            a0 = __builtin_elementwise_fma(w, (f2){xv.x, xv.x}, a0);
            a1 = __builtin_elementwise_fma(w, (f2){xv.y, xv.y}, a1);
            a2 = __builtin_elementwise_fma(w, (f2){xv.z, xv.z}, a2);
            a3 = __builtin_elementwise_fma(w, (f2){xv.w, xv.w}, a3);
        }
        // ---- in-wave K reduction: butterfly over ks bits (xor 16, 32) ----
        a0 = bfly_ks(a0);  a1 = bfly_ks(a1);
        a2 = bfly_ks(a2);  a3 = bfly_ks(a3);
        // lane ks finishes row ks (uniform-per-lane selects -> cndmask)
        {
            const bool kb0 = (ks & 1) != 0;
            const bool kb1 = (ks & 2) != 0;
            const f2 s01 = kb0 ? a1 : a0;
            const f2 s23 = kb0 ? a3 : a2;
            const f2 sel = kb1 ? s23 : s01;
            const f2 bj  = *(const f2*)&b1s[j0];
            f2 hv;
            hv.x = tanhf(sel.x + bj.x);
            hv.y = tanhf(sel.y + bj.y);
            *(f2*)&pbuf[ks][j0] = hv;      // row=ks, cols {j0,j0+1}
        }
        __syncthreads();   // B: pbuf visible; step-t xcT reads done

        // ---- GEMM2: wave wvid, h in [jb, jb+32), W2 from LDS ----
        if (loader && (t + 1 < T_))
            xcT[SD_ + lc][lr] = cpre;      // safe: xcT reads done at B
        {
            f2 q0 = {0.f, 0.f}, q1 = {0.f, 0.f}, q2 = {0.f, 0.f}, q3 = {0.f, 0.f};
            #pragma unroll
            for (int i4 = 0; i4 < CHUNK_; i4 += 4) {
                const float wa = w2s[jb + i4 + 0][sl];   // lane-consecutive
                const float wb = w2s[jb + i4 + 1][sl];
                const float wc = w2s[jb + i4 + 2][sl];
                const float wd = w2s[jb + i4 + 3][sl];
                const f2 wab = {wa, wb};
                const f2 wcd = {wc, wd};
                const float4 h0 = *(const float4*)&pbuf[0][jb + i4];  // broadcast
                const float4 h1 = *(const float4*)&pbuf[1][jb + i4];
                const float4 h2 = *(const float4*)&pbuf[2][jb + i4];
                const float4 h3 = *(const float4*)&pbuf[3][jb + i4];
                q0 = __builtin_elementwise_fma((f2){h0.x, h0.y}, wab, q0);
                q0 = __builtin_elementwise_fma((f2){h0.z, h0.w}, wcd, q0);
                q1 = __builtin_elementwise_fma((f2){h1.x, h1.y}, wab, q1);
                q1 = __builtin_elementwise_fma((f2){h1.z, h1.w}, wcd, q1);
                q2 = __builtin_elementwise_fma((f2){h2.x, h2.y}, wab, q2);
                q2 = __builtin_elementwise_fma((f2){h2.z, h2.w}, wcd, q2);
                q3 = __builtin_elementwise_fma((f2){h3.x, h3.y}, wab, q3);
                q3 = __builtin_elementwise_fma((f2){h3.z, h3.w}, wcd, q3);
            }
            part2[0][wvid][sl] = q0.x + q0.y;   // lane-consecutive
            part2[1][wvid][sl] = q1.x + q1.y;
            part2[2][wvid][sl] = q2.x + q2.y;
            part2[3][wvid][sl] = q3.x + q3.y;
        }
        __syncthreads();   // C: part2 visible

        // ---- 16-chunk reduce + state update: tid < 256 ----
        if (tid < ROWS_ * SD_) {
            float acc = part2[rf][0][sf];
            #pragma unroll
            for (int c = 1; c < 16; ++c) acc += part2[rf][c][sf];
            const float xnew = xcT[sf][rf] + DT_ * (acc + bs);
            xcT[sf][rf] = xnew;
            out[(size_t)(r0 + rf) * (T_ + 1) * SD_ + (size_t)(t + 1) * SD_ + sf] = xnew;
        }
        __syncthreads();   // D: new state visible; part2/pbuf reads done
    }
}

extern "C" void kernel_launch(void* const* d_in, const int* in_sizes, int n_in,
                              void* d_out, int out_size, void* d_ws, size_t ws_size,
                              hipStream_t stream) {
    const float* x0   = (const float*)d_in[0];
    const float* ctrl = (const float*)d_in[1];
    const float* W1   = (const float*)d_in[2];
    const float* b1   = (const float*)d_in[3];
    const float* W2   = (const float*)d_in[4];
    const float* b2   = (const float*)d_in[5];
    float* out = (float*)d_out;

    dim3 grid(B_ / ROWS_);      // 256 blocks -> 1 per CU (persistent)
    dim3 block(THREADS_);
    rollout_r13_kernel<<<grid, block, 0, stream>>>(x0, ctrl, W1, b1, W2, b2, out);
}